// Round 7
// baseline (572.716 us; speedup 1.0000x reference)
//
#include <hip/hip_runtime.h>
#include <hip/hip_fp16.h>

#define TILE 64

static inline size_t align256(size_t x) { return (x + 255) & ~(size_t)255; }

// ---------------------------------------------------------------------------
// K1: HT slab layout HT[p][n][bl], p = b/64, bl = b%64.
// ---------------------------------------------------------------------------
__global__ void k_build_ht(const float* __restrict__ pred_p,
                           const float* __restrict__ p_scale,
                           const float* __restrict__ p_mean,
                           const float* __restrict__ elev,
                           float* __restrict__ HT,
                           int N) {
    __shared__ float tile[TILE][TILE + 1];
    const int n0 = blockIdx.x * TILE;
    const int p  = blockIdx.y;
    const int b0 = p * TILE;
    const int tn = threadIdx.x % TILE;
    const int tw = threadIdx.x / TILE;

    const int n = n0 + tn;
    float sc = 0.f, mn = 0.f, el = 0.f;
    if (n < N) { sc = p_scale[n]; mn = p_mean[n]; el = elev[n]; }

    #pragma unroll
    for (int i = 0; i < TILE / 4; ++i) {
        const int bl = i * 4 + tw;
        float v = 0.f;
        if (n < N) v = pred_p[(size_t)(b0 + bl) * N + n] * sc + mn + el;
        tile[tn][bl] = v;
    }
    __syncthreads();
    #pragma unroll
    for (int i = 0; i < TILE / 4; ++i) {
        const int nl = i * 4 + tw;
        const int nn = n0 + nl;
        if (nn < N) HT[((size_t)p * N + nn) * TILE + tn] = tile[nl][tn];
    }
}

// ---------------------------------------------------------------------------
// CSR build
// ---------------------------------------------------------------------------
__global__ void k_hist(const int* __restrict__ nodes, int* __restrict__ deg, int M) {
    const int i = blockIdx.x * 256 + threadIdx.x;
    if (i < M) atomicAdd(&deg[nodes[i]], 1);
}

__global__ void k_scan1(const int* __restrict__ deg, int* __restrict__ bsum, int N) {
    __shared__ int s[256];
    const int i = blockIdx.x * 256 + threadIdx.x;
    s[threadIdx.x] = (i < N) ? deg[i] : 0;
    __syncthreads();
    #pragma unroll
    for (int off = 128; off >= 1; off >>= 1) {
        if (threadIdx.x < off) s[threadIdx.x] += s[threadIdx.x + off];
        __syncthreads();
    }
    if (threadIdx.x == 0) bsum[blockIdx.x] = s[0];
}

__global__ void k_scan2(int* __restrict__ bsum, int nb) {
    __shared__ int s[256];
    const int t = threadIdx.x;
    const int v = (t < nb) ? bsum[t] : 0;
    s[t] = v;
    __syncthreads();
    #pragma unroll
    for (int off = 1; off < 256; off <<= 1) {
        const int tmp = (t >= off) ? s[t - off] : 0;
        __syncthreads();
        s[t] += tmp;
        __syncthreads();
    }
    if (t < nb) bsum[t] = s[t] - v;
}

__global__ void k_scan3(const int* __restrict__ deg, const int* __restrict__ bsum,
                        int* __restrict__ offsets, int* __restrict__ cursor, int N) {
    __shared__ int s[256];
    const int t = threadIdx.x;
    const int i = blockIdx.x * 256 + t;
    const int v = (i < N) ? deg[i] : 0;
    s[t] = v;
    __syncthreads();
    #pragma unroll
    for (int off = 1; off < 256; off <<= 1) {
        const int tmp = (t >= off) ? s[t - off] : 0;
        __syncthreads();
        s[t] += tmp;
        __syncthreads();
    }
    const int excl = s[t] - v + bsum[blockIdx.x];
    if (i < N) { offsets[i] = excl; cursor[i] = excl; }
    if (i == N - 1) offsets[N] = excl + v;
}

__global__ void k_fill(const int* __restrict__ esrc, const int* __restrict__ edst,
                       int* __restrict__ cursor, int* __restrict__ incnode,
                       int* __restrict__ pos_src, int* __restrict__ pos_dst, int E) {
    const int e = blockIdx.x * 256 + threadIdx.x;
    if (e < E) {
        const int s = esrc[e];
        const int ps = atomicAdd(&cursor[s], 1);
        incnode[ps] = s;
        pos_src[e] = ps;
        const int d = edst[e];
        const int pd = atomicAdd(&cursor[d], 1);
        incnode[pd] = d;
        pos_dst[e] = pd;
    }
}

// ---------------------------------------------------------------------------
// K2: per (edge-tile, slab): Q from pred_f -> two signed fp16 rows (128B)
// streamed into QTperm at the edge's CSR slots; head loss via HT gathers.
// ---------------------------------------------------------------------------
__global__ void k_edges(const float* __restrict__ pred_f,
                        const float* __restrict__ f_scale,
                        const float* __restrict__ f_mean,
                        const float* __restrict__ Rcoef,
                        const int* __restrict__ esrc,
                        const int* __restrict__ edst,
                        const int* __restrict__ pos_src,
                        const int* __restrict__ pos_dst,
                        const float* __restrict__ HT,    // [NP][N][64]
                        __half* __restrict__ QTperm,     // [slots][2E][64] fp16
                        double* __restrict__ head_accum,
                        int p_base, int N, int E) {
    __shared__ float qt[TILE][TILE + 1];
    __shared__ double wsum[4];
    const int e0 = blockIdx.x * TILE;
    const int slot = blockIdx.y;
    const int p = p_base + slot;
    const int b0 = p * TILE;
    const float* __restrict__ HTp = HT + (size_t)p * N * TILE;
    __half* __restrict__ QTs = QTperm + (size_t)slot * 2 * E * TILE;
    const int te = threadIdx.x % TILE;
    const int tw = threadIdx.x / TILE;

    const int e = e0 + te;
    const float fs = f_scale[e];
    const float fm = f_mean[e];
    #pragma unroll
    for (int i = 0; i < TILE / 4; ++i) {
        const int bl = i * 4 + tw;
        qt[te][bl] = pred_f[(size_t)(b0 + bl) * E + e] * fs + fm;
    }
    __syncthreads();

    double head = 0.0;
    const int bl = te;
    #pragma unroll
    for (int j = 0; j < TILE / 4; ++j) {
        const int el = tw * 16 + j;      // wave-uniform edge
        const int ee = e0 + el;
        const int s = esrc[ee];
        const int d = edst[ee];
        const int ps = pos_src[ee];
        const int pd = pos_dst[ee];
        const float q = qt[el][bl];

        QTs[(size_t)ps * TILE + bl] = __float2half_rn(-q);  // outflow slot
        QTs[(size_t)pd * TILE + bl] = __float2half_rn(q);   // inflow slot

        const float hs = HTp[(size_t)s * TILE + bl];
        const float hd = HTp[(size_t)d * TILE + bl];
        const float aq = fabsf(q);
        const float pw = exp2f(0.852f * __log2f(aq));   // |q|^0.852
        const float fr = Rcoef[ee] * q * pw;
        const float t = (hs - hd) - fr;
        head += (double)t * (double)t;
    }

    #pragma unroll
    for (int off = 32; off >= 1; off >>= 1)
        head += __shfl_down(head, off, 64);
    if ((threadIdx.x & 63) == 0) wsum[threadIdx.x >> 6] = head;
    __syncthreads();
    if (threadIdx.x == 0)
        atomicAdd(head_accum, wsum[0] + wsum[1] + wsum[2] + wsum[3]);
}

// ---------------------------------------------------------------------------
// K3: per (node-tile, slab): stream the block's contiguous CSR range of
// signed fp16 Q rows.  16-lane groups load 8B each (one wave-instr = 4 rows
// = 512B contiguous), unroll x4 -> 2KB in flight per wave.  ds_add into
// qacc[node][batch]; fused mass loss.
// ---------------------------------------------------------------------------
__global__ void k_node(const float* __restrict__ true_d,
                       const float* __restrict__ d_scale,
                       const float* __restrict__ d_mean,
                       const __half* __restrict__ QTperm,  // [slots][2E][64]
                       const int* __restrict__ offsets,
                       const int* __restrict__ incnode,
                       double* __restrict__ mass_accum,
                       int p_base, int N, int E) {
    __shared__ float qacc[TILE][TILE + 1];
    __shared__ float dt[TILE][TILE + 1];   // dt[node_local][batch_local]
    __shared__ double wsum[4];
    const int n0 = blockIdx.x * TILE;
    const int slot = blockIdx.y;
    const int b0 = (p_base + slot) * TILE;
    const __half* __restrict__ QTs = QTperm + (size_t)slot * 2 * E * TILE;
    const int tid = threadIdx.x;
    const int tn = tid % TILE;           // lane = batch (for init / mass)
    const int tw = tid / TILE;           // wave
    const int g  = (tid >> 4) & 3;       // 16-lane group within wave
    const int li = tid & 15;             // lane in group (owns cols 4li..4li+3)

    const int n = n0 + tn;
    float sc = 0.f, mn = 0.f;
    if (n < N) { sc = d_scale[n]; mn = d_mean[n]; }
    #pragma unroll
    for (int i = 0; i < TILE / 4; ++i) {
        const int r = i * 4 + tw;
        qacc[r][tn] = 0.f;
        float v = 0.f;
        if (n < N) v = true_d[(size_t)(b0 + r) * N + n] * sc + mn;
        dt[tn][r] = v;                   // [node][batch]
    }
    __syncthreads();

    const int nhi = (n0 + TILE < N) ? (n0 + TILE) : N;
    const int beg = offsets[n0];
    const int end = offsets[nhi];
    const int total = end - beg;
    const int nmain = (total / 64) * 64;     // 64 rows per block-iter

    for (int base = beg; base < beg + nmain; base += 64) {
        int   rows[4];
        uint2 raw[4];
        #pragma unroll
        for (int u = 0; u < 4; ++u) {
            const int k = base + tw * 16 + u * 4 + g;
            raw[u] = *reinterpret_cast<const uint2*>(QTs + (size_t)k * TILE + li * 4);
            rows[u] = incnode[k] - n0;
        }
        #pragma unroll
        for (int u = 0; u < 4; ++u) {
            const __half2 h01 = *reinterpret_cast<const __half2*>(&raw[u].x);
            const __half2 h23 = *reinterpret_cast<const __half2*>(&raw[u].y);
            const float2 f01 = __half22float2(h01);
            const float2 f23 = __half22float2(h23);
            float* qr = &qacc[rows[u]][li * 4];
            atomicAdd(qr + 0, f01.x);
            atomicAdd(qr + 1, f01.y);
            atomicAdd(qr + 2, f23.x);
            atomicAdd(qr + 3, f23.y);
        }
    }
    // tail: 16 rows per iter (one per group x wave)
    for (int k0 = beg + nmain; k0 < end; k0 += 16) {
        const int k = k0 + tw * 4 + g;
        if (k < end) {
            const uint2 raw = *reinterpret_cast<const uint2*>(QTs + (size_t)k * TILE + li * 4);
            const int row = incnode[k] - n0;
            const __half2 h01 = *reinterpret_cast<const __half2*>(&raw.x);
            const __half2 h23 = *reinterpret_cast<const __half2*>(&raw.y);
            const float2 f01 = __half22float2(h01);
            const float2 f23 = __half22float2(h23);
            float* qr = &qacc[row][li * 4];
            atomicAdd(qr + 0, f01.x);
            atomicAdd(qr + 1, f01.y);
            atomicAdd(qr + 2, f23.x);
            atomicAdd(qr + 3, f23.y);
        }
    }
    __syncthreads();

    double m = 0.0;
    #pragma unroll
    for (int i = 0; i < TILE / 4; ++i) {
        const int r = i * 4 + tw;        // node row
        if (n0 + r < N) {
            const float t = qacc[r][tn] - dt[r][tn];
            m += (double)t * (double)t;
        }
    }
    #pragma unroll
    for (int off = 32; off >= 1; off >>= 1)
        m += __shfl_down(m, off, 64);
    if ((threadIdx.x & 63) == 0) wsum[threadIdx.x >> 6] = m;
    __syncthreads();
    if (threadIdx.x == 0)
        atomicAdd(mass_accum, wsum[0] + wsum[1] + wsum[2] + wsum[3]);
}

// ---------------------------------------------------------------------------
__global__ void k_final(const double* __restrict__ accum,
                        float* __restrict__ out,
                        double inv_mass_count, double inv_head_count) {
    out[0] = (float)(accum[0] * inv_mass_count);
    out[1] = (float)(accum[1] * inv_head_count);
}

extern "C" void kernel_launch(void* const* d_in, const int* in_sizes, int n_in,
                              void* d_out, int out_size, void* d_ws, size_t ws_size,
                              hipStream_t stream) {
    const float* pred_p  = (const float*)d_in[0];
    const float* pred_f  = (const float*)d_in[1];
    const float* true_d  = (const float*)d_in[2];
    const float* p_mean  = (const float*)d_in[3];
    const float* p_scale = (const float*)d_in[4];
    const float* f_mean  = (const float*)d_in[5];
    const float* f_scale = (const float*)d_in[6];
    const float* d_mean  = (const float*)d_in[7];
    const float* d_scale = (const float*)d_in[8];
    const float* elev    = (const float*)d_in[9];
    const float* Rcoef   = (const float*)d_in[10];
    const int*   eidx    = (const int*)d_in[11];

    const int N = in_sizes[3];              // 50000
    const int E = in_sizes[10];             // 128000
    const int B = in_sizes[0] / N;          // 256
    const int NP = B / TILE;                // 4 batch slabs

    const int* esrc = eidx;
    const int* edst = eidx + E;

    const size_t fixed =
        align256((size_t)NP * N * TILE * 4) +      // HT
        align256((size_t)2 * E * 4) +              // incnode
        align256((size_t)E * 4) +                  // pos_src
        align256((size_t)E * 4) +                  // pos_dst
        align256((size_t)(N + 1) * 4) +            // offsets
        align256((size_t)N * 4) +                  // cursor
        align256((size_t)N * 4) +                  // deg
        align256(256 * 4) +                        // bsum
        align256(2 * sizeof(double));              // accum
    const size_t qt_slab = align256((size_t)2 * E * TILE * 2);  // fp16: 32.8 MB
    const int SLOTS = (ws_size >= fixed + (size_t)NP * qt_slab) ? NP : 1;

    char* ws = (char*)d_ws;
    size_t off = 0;
    float*  HT     = (float*)(ws + off); off = align256(off + (size_t)NP * N * TILE * 4);
    __half* QTperm = (__half*)(ws + off); off += (size_t)SLOTS * qt_slab;
    int* incnode  = (int*)(ws + off); off = align256(off + (size_t)2 * E * 4);
    int* pos_src  = (int*)(ws + off); off = align256(off + (size_t)E * 4);
    int* pos_dst  = (int*)(ws + off); off = align256(off + (size_t)E * 4);
    int* offsets  = (int*)(ws + off); off = align256(off + (size_t)(N + 1) * 4);
    int* cursor   = (int*)(ws + off); off = align256(off + (size_t)N * 4);
    const size_t zero_beg = off;
    int* deg      = (int*)(ws + off); off = align256(off + (size_t)N * 4);
    int* bsum     = (int*)(ws + off); off = align256(off + 256 * 4);
    double* accum = (double*)(ws + off); off += 2 * sizeof(double);
    const size_t zero_len = off - zero_beg;

    hipMemsetAsync(ws + zero_beg, 0, zero_len, stream);

    const int gn = (N + TILE - 1) / TILE;   // 782
    const int ge = E / TILE;                // 2000
    const int nb = (N + 255) / 256;         // 196

    k_build_ht<<<dim3(gn, NP), 256, 0, stream>>>(pred_p, p_scale, p_mean, elev,
                                                 HT, N);
    k_hist <<<(2 * E + 255) / 256, 256, 0, stream>>>(eidx, deg, 2 * E);
    k_scan1<<<nb, 256, 0, stream>>>(deg, bsum, N);
    k_scan2<<<1, 256, 0, stream>>>(bsum, nb);
    k_scan3<<<nb, 256, 0, stream>>>(deg, bsum, offsets, cursor, N);
    k_fill <<<(E + 255) / 256, 256, 0, stream>>>(esrc, edst, cursor, incnode,
                                                 pos_src, pos_dst, E);

    if (SLOTS == NP) {
        k_edges<<<dim3(ge, NP), 256, 0, stream>>>(pred_f, f_scale, f_mean, Rcoef,
                                                  esrc, edst, pos_src, pos_dst,
                                                  HT, QTperm, accum + 1, 0, N, E);
        k_node <<<dim3(gn, NP), 256, 0, stream>>>(true_d, d_scale, d_mean, QTperm,
                                                  offsets, incnode,
                                                  accum + 0, 0, N, E);
    } else {
        for (int p = 0; p < NP; ++p) {
            k_edges<<<dim3(ge, 1), 256, 0, stream>>>(pred_f, f_scale, f_mean,
                                                     Rcoef, esrc, edst,
                                                     pos_src, pos_dst,
                                                     HT, QTperm, accum + 1, p, N, E);
            k_node <<<dim3(gn, 1), 256, 0, stream>>>(true_d, d_scale, d_mean,
                                                     QTperm, offsets, incnode,
                                                     accum + 0, p, N, E);
        }
    }

    k_final<<<1, 1, 0, stream>>>(accum, (float*)d_out,
                                 1.0 / ((double)B * (double)N),
                                 1.0 / ((double)B * (double)E));
}

// Round 8
// 557.746 us; speedup vs baseline: 1.0268x; 1.0268x over previous
//
#include <hip/hip_runtime.h>
#include <hip/hip_fp16.h>

#define TILE 64
#define CHUNK 128   // CSR rows staged per LDS chunk (128 rows x 128 B = 16 KB)

static inline size_t align256(size_t x) { return (x + 255) & ~(size_t)255; }

#define GLOAD_LDS(gptr, lptr, sz)                                              \
    __builtin_amdgcn_global_load_lds(                                          \
        (const __attribute__((address_space(1))) unsigned int*)(gptr),         \
        (__attribute__((address_space(3))) unsigned int*)(lptr), (sz), 0, 0)

// ---------------------------------------------------------------------------
// K1: HT slab layout HT[p][n][bl], p = b/64, bl = b%64.
// ---------------------------------------------------------------------------
__global__ void k_build_ht(const float* __restrict__ pred_p,
                           const float* __restrict__ p_scale,
                           const float* __restrict__ p_mean,
                           const float* __restrict__ elev,
                           float* __restrict__ HT,
                           int N) {
    __shared__ float tile[TILE][TILE + 1];
    const int n0 = blockIdx.x * TILE;
    const int p  = blockIdx.y;
    const int b0 = p * TILE;
    const int tn = threadIdx.x % TILE;
    const int tw = threadIdx.x / TILE;

    const int n = n0 + tn;
    float sc = 0.f, mn = 0.f, el = 0.f;
    if (n < N) { sc = p_scale[n]; mn = p_mean[n]; el = elev[n]; }

    #pragma unroll
    for (int i = 0; i < TILE / 4; ++i) {
        const int bl = i * 4 + tw;
        float v = 0.f;
        if (n < N) v = pred_p[(size_t)(b0 + bl) * N + n] * sc + mn + el;
        tile[tn][bl] = v;
    }
    __syncthreads();
    #pragma unroll
    for (int i = 0; i < TILE / 4; ++i) {
        const int nl = i * 4 + tw;
        const int nn = n0 + nl;
        if (nn < N) HT[((size_t)p * N + nn) * TILE + tn] = tile[nl][tn];
    }
}

// ---------------------------------------------------------------------------
// CSR build
// ---------------------------------------------------------------------------
__global__ void k_hist(const int* __restrict__ nodes, int* __restrict__ deg, int M) {
    const int i = blockIdx.x * 256 + threadIdx.x;
    if (i < M) atomicAdd(&deg[nodes[i]], 1);
}

__global__ void k_scan1(const int* __restrict__ deg, int* __restrict__ bsum, int N) {
    __shared__ int s[256];
    const int i = blockIdx.x * 256 + threadIdx.x;
    s[threadIdx.x] = (i < N) ? deg[i] : 0;
    __syncthreads();
    #pragma unroll
    for (int off = 128; off >= 1; off >>= 1) {
        if (threadIdx.x < off) s[threadIdx.x] += s[threadIdx.x + off];
        __syncthreads();
    }
    if (threadIdx.x == 0) bsum[blockIdx.x] = s[0];
}

__global__ void k_scan2(int* __restrict__ bsum, int nb) {
    __shared__ int s[256];
    const int t = threadIdx.x;
    const int v = (t < nb) ? bsum[t] : 0;
    s[t] = v;
    __syncthreads();
    #pragma unroll
    for (int off = 1; off < 256; off <<= 1) {
        const int tmp = (t >= off) ? s[t - off] : 0;
        __syncthreads();
        s[t] += tmp;
        __syncthreads();
    }
    if (t < nb) bsum[t] = s[t] - v;
}

__global__ void k_scan3(const int* __restrict__ deg, const int* __restrict__ bsum,
                        int* __restrict__ offsets, int* __restrict__ cursor, int N) {
    __shared__ int s[256];
    const int t = threadIdx.x;
    const int i = blockIdx.x * 256 + t;
    const int v = (i < N) ? deg[i] : 0;
    s[t] = v;
    __syncthreads();
    #pragma unroll
    for (int off = 1; off < 256; off <<= 1) {
        const int tmp = (t >= off) ? s[t - off] : 0;
        __syncthreads();
        s[t] += tmp;
        __syncthreads();
    }
    const int excl = s[t] - v + bsum[blockIdx.x];
    if (i < N) { offsets[i] = excl; cursor[i] = excl; }
    if (i == N - 1) offsets[N] = excl + v;
}

__global__ void k_fill(const int* __restrict__ esrc, const int* __restrict__ edst,
                       int* __restrict__ cursor, int* __restrict__ incnode,
                       int* __restrict__ pos_src, int* __restrict__ pos_dst, int E) {
    const int e = blockIdx.x * 256 + threadIdx.x;
    if (e < E) {
        const int s = esrc[e];
        const int ps = atomicAdd(&cursor[s], 1);
        incnode[ps] = s;
        pos_src[e] = ps;
        const int d = edst[e];
        const int pd = atomicAdd(&cursor[d], 1);
        incnode[pd] = d;
        pos_dst[e] = pd;
    }
}

// ---------------------------------------------------------------------------
// K2: per (edge-tile, slab): Q from pred_f -> two signed fp16 rows (128B)
// streamed into QTperm at the edge's CSR slots; head loss via HT gathers.
// ---------------------------------------------------------------------------
__global__ void k_edges(const float* __restrict__ pred_f,
                        const float* __restrict__ f_scale,
                        const float* __restrict__ f_mean,
                        const float* __restrict__ Rcoef,
                        const int* __restrict__ esrc,
                        const int* __restrict__ edst,
                        const int* __restrict__ pos_src,
                        const int* __restrict__ pos_dst,
                        const float* __restrict__ HT,    // [NP][N][64]
                        __half* __restrict__ QTperm,     // [slots][2E][64] fp16
                        double* __restrict__ head_accum,
                        int p_base, int N, int E) {
    __shared__ float qt[TILE][TILE + 1];
    __shared__ double wsum[4];
    const int e0 = blockIdx.x * TILE;
    const int slot = blockIdx.y;
    const int p = p_base + slot;
    const int b0 = p * TILE;
    const float* __restrict__ HTp = HT + (size_t)p * N * TILE;
    __half* __restrict__ QTs = QTperm + (size_t)slot * 2 * E * TILE;
    const int te = threadIdx.x % TILE;
    const int tw = threadIdx.x / TILE;

    const int e = e0 + te;
    const float fs = f_scale[e];
    const float fm = f_mean[e];
    #pragma unroll
    for (int i = 0; i < TILE / 4; ++i) {
        const int bl = i * 4 + tw;
        qt[te][bl] = pred_f[(size_t)(b0 + bl) * E + e] * fs + fm;
    }
    __syncthreads();

    double head = 0.0;
    const int bl = te;
    #pragma unroll
    for (int j = 0; j < TILE / 4; ++j) {
        const int el = tw * 16 + j;      // wave-uniform edge
        const int ee = e0 + el;
        const int s = esrc[ee];
        const int d = edst[ee];
        const int ps = pos_src[ee];
        const int pd = pos_dst[ee];
        const float q = qt[el][bl];

        QTs[(size_t)ps * TILE + bl] = __float2half_rn(-q);  // outflow slot
        QTs[(size_t)pd * TILE + bl] = __float2half_rn(q);   // inflow slot

        const float hs = HTp[(size_t)s * TILE + bl];
        const float hd = HTp[(size_t)d * TILE + bl];
        const float aq = fabsf(q);
        const float pw = exp2f(0.852f * __log2f(aq));   // |q|^0.852
        const float fr = Rcoef[ee] * q * pw;
        const float t = (hs - hd) - fr;
        head += (double)t * (double)t;
    }

    #pragma unroll
    for (int off = 32; off >= 1; off >>= 1)
        head += __shfl_down(head, off, 64);
    if ((threadIdx.x & 63) == 0) wsum[threadIdx.x >> 6] = head;
    __syncthreads();
    if (threadIdx.x == 0)
        atomicAdd(head_accum, wsum[0] + wsum[1] + wsum[2] + wsum[3]);
}

// ---------------------------------------------------------------------------
// K3: per (node-tile, slab).  All global->LDS movement is async DMA
// (global_load_lds): no VGPR round-trip, ~20 loads in flight per wave
// regardless of register allocation.  Per chunk: stage 128 CSR rows (16 KB,
// linear) + their incnode ids, barrier (drains vmcnt), then LDS->LDS
// accumulate: ds_read half2 -> 2x ds_add_f32 into qacc[node][batch].
// true_d rows staged once in the prologue (per-row-linear DMA into padded
// LDS rows).  Fused mass loss at the end.
// ---------------------------------------------------------------------------
__global__ void k_node(const float* __restrict__ true_d,
                       const float* __restrict__ d_scale,
                       const float* __restrict__ d_mean,
                       const __half* __restrict__ QTperm,  // [slots][2E][64]
                       const int* __restrict__ offsets,
                       const int* __restrict__ incnode,
                       double* __restrict__ mass_accum,
                       int p_base, int N, int E, int B) {
    __shared__ __align__(16) __half stagedQ[CHUNK * 64];   // 16 KB
    __shared__ int rows_lds[CHUNK];                        // 512 B
    __shared__ float qacc[TILE][TILE + 1];                 // [node][batch]
    __shared__ float dtraw[TILE][TILE + 1];                // [batch][node] raw
    __shared__ float dsc[TILE], dmn[TILE];
    __shared__ double wsum[4];

    const int n0 = blockIdx.x * TILE;
    const int slot = blockIdx.y;
    const int b0 = (p_base + slot) * TILE;
    const __half* __restrict__ QTs = QTperm + (size_t)slot * 2 * E * TILE;
    const int tid = threadIdx.x;
    const int lane = tid & 63;
    const int w = tid >> 6;

    // per-node params -> LDS
    if (tid < TILE) {
        const int n = n0 + tid;
        dsc[tid] = (n < N) ? d_scale[n] : 0.f;
        dmn[tid] = (n < N) ? d_mean[n] : 0.f;
    }
    // zero qacc
    #pragma unroll
    for (int i = 0; i < TILE / 4; ++i) qacc[i * 4 + w][lane] = 0.f;

    // stage true_d batch-rows: row r -> dtraw[r][0..63] (per-row linear DMA;
    // per-lane source clamp keeps the last node-tile in bounds)
    {
        const size_t gmax = (size_t)B * N - 1;
        #pragma unroll
        for (int i = 0; i < 16; ++i) {
            const int r = w * 16 + i;
            size_t gidx = (size_t)(b0 + r) * N + n0 + lane;
            if (gidx > gmax) gidx = gmax;
            GLOAD_LDS(true_d + gidx, &dtraw[r][0], 4);
        }
    }

    const int nhi = (n0 + TILE < N) ? (n0 + TILE) : N;
    const int beg = offsets[n0];
    const int end = offsets[nhi];

    // async stage of one CSR chunk: Q rows (1 KB per DMA instr) + node ids
    auto stage_chunk = [&](int ck) {
        const int bytes = (end - ck) * 128;      // Q bytes still needed
        #pragma unroll
        for (int i = 0; i < 4; ++i) {
            const int kb = w * 4 + i;            // KB index within chunk
            if (kb * 1024 < bytes) {
                const char* g = (const char*)(QTs + (size_t)ck * TILE)
                                + kb * 1024 + lane * 16;
                GLOAD_LDS(g, (char*)stagedQ + kb * 1024, 16);
            }
        }
        if (w < 2) {                             // 2 x 64 ints = 128 row ids
            const int base = w * 64;
            if (ck + base < end)
                GLOAD_LDS(incnode + ck + base + lane, &rows_lds[base], 4);
        }
    };

    if (beg < end) stage_chunk(beg);

    const int c2 = tid & 31;                     // half2 column (batch pair)
    const int rt = tid >> 5;                     // row-thread 0..7
    for (int ck = beg; ck < end; ck += CHUNK) {
        asm volatile("s_waitcnt vmcnt(0)" ::: "memory");
        __syncthreads();                         // staged data visible to all
        const int crows = (end - ck < CHUNK) ? (end - ck) : CHUNK;
        for (int r = rt; r < crows; r += 8) {
            const int tr = rows_lds[r] - n0;     // target node row
            const __half2 h = ((const __half2*)stagedQ)[r * 32 + c2];
            const float2 f = __half22float2(h);
            atomicAdd(&qacc[tr][c2 * 2],     f.x);
            atomicAdd(&qacc[tr][c2 * 2 + 1], f.y);
        }
        __syncthreads();                         // done reading staged buffer
        if (ck + CHUNK < end) stage_chunk(ck + CHUNK);
    }
    if (beg >= end) {                            // still need dtraw drained
        asm volatile("s_waitcnt vmcnt(0)" ::: "memory");
    }
    __syncthreads();

    // fused mass loss: d = dtraw*scale+mean, t = qacc - d
    double m = 0.0;
    #pragma unroll
    for (int i = 0; i < TILE / 4; ++i) {
        const int r = i * 4 + w;                 // node row (wave-uniform)
        if (n0 + r < N) {
            const float dv = dtraw[lane][r] * dsc[r] + dmn[r];
            const float t = qacc[r][lane] - dv;
            m += (double)t * (double)t;
        }
    }
    #pragma unroll
    for (int off = 32; off >= 1; off >>= 1)
        m += __shfl_down(m, off, 64);
    if ((tid & 63) == 0) wsum[tid >> 6] = m;
    __syncthreads();
    if (tid == 0)
        atomicAdd(mass_accum, wsum[0] + wsum[1] + wsum[2] + wsum[3]);
}

// ---------------------------------------------------------------------------
__global__ void k_final(const double* __restrict__ accum,
                        float* __restrict__ out,
                        double inv_mass_count, double inv_head_count) {
    out[0] = (float)(accum[0] * inv_mass_count);
    out[1] = (float)(accum[1] * inv_head_count);
}

extern "C" void kernel_launch(void* const* d_in, const int* in_sizes, int n_in,
                              void* d_out, int out_size, void* d_ws, size_t ws_size,
                              hipStream_t stream) {
    const float* pred_p  = (const float*)d_in[0];
    const float* pred_f  = (const float*)d_in[1];
    const float* true_d  = (const float*)d_in[2];
    const float* p_mean  = (const float*)d_in[3];
    const float* p_scale = (const float*)d_in[4];
    const float* f_mean  = (const float*)d_in[5];
    const float* f_scale = (const float*)d_in[6];
    const float* d_mean  = (const float*)d_in[7];
    const float* d_scale = (const float*)d_in[8];
    const float* elev    = (const float*)d_in[9];
    const float* Rcoef   = (const float*)d_in[10];
    const int*   eidx    = (const int*)d_in[11];

    const int N = in_sizes[3];              // 50000
    const int E = in_sizes[10];             // 128000
    const int B = in_sizes[0] / N;          // 256
    const int NP = B / TILE;                // 4 batch slabs

    const int* esrc = eidx;
    const int* edst = eidx + E;

    const size_t fixed =
        align256((size_t)NP * N * TILE * 4) +      // HT
        align256((size_t)2 * E * 4) +              // incnode
        align256((size_t)E * 4) +                  // pos_src
        align256((size_t)E * 4) +                  // pos_dst
        align256((size_t)(N + 1) * 4) +            // offsets
        align256((size_t)N * 4) +                  // cursor
        align256((size_t)N * 4) +                  // deg
        align256(256 * 4) +                        // bsum
        align256(2 * sizeof(double));              // accum
    const size_t qt_slab = align256((size_t)2 * E * TILE * 2);  // fp16: 32.8 MB
    const int SLOTS = (ws_size >= fixed + (size_t)NP * qt_slab) ? NP : 1;

    char* ws = (char*)d_ws;
    size_t off = 0;
    float*  HT     = (float*)(ws + off); off = align256(off + (size_t)NP * N * TILE * 4);
    __half* QTperm = (__half*)(ws + off); off += (size_t)SLOTS * qt_slab;
    int* incnode  = (int*)(ws + off); off = align256(off + (size_t)2 * E * 4);
    int* pos_src  = (int*)(ws + off); off = align256(off + (size_t)E * 4);
    int* pos_dst  = (int*)(ws + off); off = align256(off + (size_t)E * 4);
    int* offsets  = (int*)(ws + off); off = align256(off + (size_t)(N + 1) * 4);
    int* cursor   = (int*)(ws + off); off = align256(off + (size_t)N * 4);
    const size_t zero_beg = off;
    int* deg      = (int*)(ws + off); off = align256(off + (size_t)N * 4);
    int* bsum     = (int*)(ws + off); off = align256(off + 256 * 4);
    double* accum = (double*)(ws + off); off += 2 * sizeof(double);
    const size_t zero_len = off - zero_beg;

    hipMemsetAsync(ws + zero_beg, 0, zero_len, stream);

    const int gn = (N + TILE - 1) / TILE;   // 782
    const int ge = E / TILE;                // 2000
    const int nb = (N + 255) / 256;         // 196

    k_build_ht<<<dim3(gn, NP), 256, 0, stream>>>(pred_p, p_scale, p_mean, elev,
                                                 HT, N);
    k_hist <<<(2 * E + 255) / 256, 256, 0, stream>>>(eidx, deg, 2 * E);
    k_scan1<<<nb, 256, 0, stream>>>(deg, bsum, N);
    k_scan2<<<1, 256, 0, stream>>>(bsum, nb);
    k_scan3<<<nb, 256, 0, stream>>>(deg, bsum, offsets, cursor, N);
    k_fill <<<(E + 255) / 256, 256, 0, stream>>>(esrc, edst, cursor, incnode,
                                                 pos_src, pos_dst, E);

    if (SLOTS == NP) {
        k_edges<<<dim3(ge, NP), 256, 0, stream>>>(pred_f, f_scale, f_mean, Rcoef,
                                                  esrc, edst, pos_src, pos_dst,
                                                  HT, QTperm, accum + 1, 0, N, E);
        k_node <<<dim3(gn, NP), 256, 0, stream>>>(true_d, d_scale, d_mean, QTperm,
                                                  offsets, incnode,
                                                  accum + 0, 0, N, E, B);
    } else {
        for (int p = 0; p < NP; ++p) {
            k_edges<<<dim3(ge, 1), 256, 0, stream>>>(pred_f, f_scale, f_mean,
                                                     Rcoef, esrc, edst,
                                                     pos_src, pos_dst,
                                                     HT, QTperm, accum + 1, p, N, E);
            k_node <<<dim3(gn, 1), 256, 0, stream>>>(true_d, d_scale, d_mean,
                                                     QTperm, offsets, incnode,
                                                     accum + 0, p, N, E, B);
        }
    }

    k_final<<<1, 1, 0, stream>>>(accum, (float*)d_out,
                                 1.0 / ((double)B * (double)N),
                                 1.0 / ((double)B * (double)E));
}

// Round 10
// 256.994 us; speedup vs baseline: 2.2285x; 2.1703x over previous
//
#include <hip/hip_runtime.h>
#include <hip/hip_fp16.h>

#define TILE 64

// packed fp16 atomic add (global_atomic_pk_add_f16)
typedef _Float16 f16x2 __attribute__((ext_vector_type(2)));
__device__ inline void pk_add(__half2* p, float a, float b) {
#if __has_builtin(__builtin_amdgcn_global_atomic_fadd_v2f16)
    f16x2 v; v[0] = (_Float16)a; v[1] = (_Float16)b;
    __builtin_amdgcn_global_atomic_fadd_v2f16(
        (__attribute__((address_space(1))) f16x2*)p, v);
#else
    __half2 v = __floats2half2_rn(a, b);
    unsafeAtomicAdd(p, v);
#endif
}

// ---------------------------------------------------------------------------
// Kernel 1: HT[n*B + b] = pred_p[b*N + n] * p_scale[n] + p_mean[n] + elev[n]
// 64x64 LDS transpose tile; both global sides coalesced.
// ---------------------------------------------------------------------------
__global__ void k_build_ht(const float* __restrict__ pred_p,
                           const float* __restrict__ p_scale,
                           const float* __restrict__ p_mean,
                           const float* __restrict__ elev,
                           float* __restrict__ HT,
                           int B, int N) {
    __shared__ float tile[TILE][TILE + 1];
    const int n0 = blockIdx.x * TILE;
    const int b0 = blockIdx.y * TILE;
    const int tn = threadIdx.x % TILE;   // 0..63
    const int tw = threadIdx.x / TILE;   // 0..3

    const int n = n0 + tn;
    float sc = 0.f, mn = 0.f, el = 0.f;
    if (n < N) { sc = p_scale[n]; mn = p_mean[n]; el = elev[n]; }

    #pragma unroll
    for (int i = 0; i < TILE / 4; ++i) {
        const int bl = i * 4 + tw;
        float v = 0.f;
        if (n < N) v = pred_p[(size_t)(b0 + bl) * N + n] * sc + mn + el;
        tile[tn][bl] = v;
    }
    __syncthreads();
    #pragma unroll
    for (int i = 0; i < TILE / 4; ++i) {
        const int nl = i * 4 + tw;
        const int nn = n0 + nl;
        if (nn < N) HT[(size_t)nn * B + b0 + tn] = tile[nl][tn];
    }
}

// ---------------------------------------------------------------------------
// Kernel 2: per-edge fused work (round-3 structure, fp16 pk atomics).
//   Q[b][e] staged in LDS (transposed);
//   head loss: t = (HT[src*B+b]-HT[dst*B+b]) - R*Q*|Q|^0.852 -> f64 reduce;
//   mass scatter: acc2[dst][pair] += (q0,q1); acc2[src][pair] -= (q0,q1)
//                 via global_atomic_pk_add_f16, lanes 0..31, 128B/scatter.
// ---------------------------------------------------------------------------
__global__ void k_edges(const float* __restrict__ pred_f,
                        const float* __restrict__ f_scale,
                        const float* __restrict__ f_mean,
                        const float* __restrict__ Rcoef,
                        const int* __restrict__ esrc,
                        const int* __restrict__ edst,
                        const float* __restrict__ HT,
                        __half2* __restrict__ acc2,   // [N][128] pairs (fp16)
                        double* __restrict__ head_accum,
                        int B, int E) {
    __shared__ float qt[TILE][TILE + 1];   // [e_local][b_local]
    __shared__ double wsum[4];
    const int e0 = blockIdx.x * TILE;
    const int b0 = blockIdx.y * TILE;
    const int te = threadIdx.x % TILE;
    const int tw = threadIdx.x / TILE;

    const int e = e0 + te;
    const float fs = f_scale[e];
    const float fm = f_mean[e];
    #pragma unroll
    for (int i = 0; i < TILE / 4; ++i) {
        const int bl = i * 4 + tw;
        qt[te][bl] = pred_f[(size_t)(b0 + bl) * E + e] * fs + fm;
    }
    __syncthreads();

    double head = 0.0;
    const int bl = te;                 // lane -> batch (coalesced HT/acc)
    const int pair0 = b0 >> 1;         // first half2 cell of this slab
    const float* HTb = HT + b0 + bl;

    #pragma unroll
    for (int j = 0; j < TILE / 4; ++j) {
        const int el = tw * 16 + j;    // wave-uniform edge index
        const int ee = e0 + el;
        const int s = esrc[ee];
        const int d = edst[ee];
        const float q = qt[el][bl];

        // issue gathers first so they overlap the VALU below
        const float hs = HTb[(size_t)s * B];
        const float hd = HTb[(size_t)d * B];

        // mass scatter: lanes 0..31 each cover a batch pair (2 fp16)
        if (bl < 32) {
            const float q0 = qt[el][2 * bl];
            const float q1 = qt[el][2 * bl + 1];
            pk_add(&acc2[(size_t)d * 128 + pair0 + bl],  q0,  q1);
            pk_add(&acc2[(size_t)s * 128 + pair0 + bl], -q0, -q1);
        }

        // |q|^0.852 = exp2(0.852*log2(|q|));  log2(0)=-inf -> exp2(-inf)=0
        const float aq = fabsf(q);
        const float pw = exp2f(0.852f * __log2f(aq));
        const float fr = Rcoef[ee] * q * pw;
        const float t = (hs - hd) - fr;
        head += (double)t * (double)t;
    }

    #pragma unroll
    for (int off = 32; off >= 1; off >>= 1)
        head += __shfl_down(head, off, 64);
    if ((threadIdx.x & 63) == 0) wsum[threadIdx.x >> 6] = head;
    __syncthreads();
    if (threadIdx.x == 0)
        atomicAdd(head_accum, wsum[0] + wsum[1] + wsum[2] + wsum[3]);
}

// ---------------------------------------------------------------------------
// Kernel 3: loss_mass.  q_net read as half2 pairs from acc2; d from
// transposed true_d staged in LDS.
// ---------------------------------------------------------------------------
__global__ void k_mass(const float* __restrict__ true_d,
                       const float* __restrict__ d_scale,
                       const float* __restrict__ d_mean,
                       const __half2* __restrict__ acc2,  // [N][128]
                       double* __restrict__ mass_accum,
                       int B, int N) {
    __shared__ float dt[TILE][TILE + 1];   // [node_local][batch_local]
    __shared__ double wsum[4];
    const int n0 = blockIdx.x * TILE;
    const int b0 = blockIdx.y * TILE;
    const int tn = threadIdx.x % TILE;
    const int tw = threadIdx.x / TILE;

    const int n = n0 + tn;
    float sc = 0.f, mn = 0.f;
    if (n < N) { sc = d_scale[n]; mn = d_mean[n]; }
    #pragma unroll
    for (int i = 0; i < TILE / 4; ++i) {
        const int bl = i * 4 + tw;
        float v = 0.f;
        if (n < N) v = true_d[(size_t)(b0 + bl) * N + n] * sc + mn;
        dt[tn][bl] = v;
    }
    __syncthreads();

    double m = 0.0;
    const int tn2 = threadIdx.x & 31;      // pair column (2 batches)
    const int tg  = threadIdx.x >> 5;      // 0..7 row groups
    const int pair0 = b0 >> 1;
    #pragma unroll
    for (int j = 0; j < 8; ++j) {
        const int nl = j * 8 + tg;         // node row 0..63
        const int nn = n0 + nl;
        if (nn < N) {
            const __half2 h = acc2[(size_t)nn * 128 + pair0 + tn2];
            const float2 f = __half22float2(h);
            const float t0 = f.x - dt[nl][2 * tn2];
            const float t1 = f.y - dt[nl][2 * tn2 + 1];
            m += (double)t0 * (double)t0 + (double)t1 * (double)t1;
        }
    }
    #pragma unroll
    for (int off = 32; off >= 1; off >>= 1)
        m += __shfl_down(m, off, 64);
    if ((threadIdx.x & 63) == 0) wsum[threadIdx.x >> 6] = m;
    __syncthreads();
    if (threadIdx.x == 0)
        atomicAdd(mass_accum, wsum[0] + wsum[1] + wsum[2] + wsum[3]);
}

// ---------------------------------------------------------------------------
__global__ void k_final(const double* __restrict__ accum,
                        float* __restrict__ out,
                        double inv_mass_count, double inv_head_count) {
    out[0] = (float)(accum[0] * inv_mass_count);   // loss_mass
    out[1] = (float)(accum[1] * inv_head_count);   // loss_head
}

extern "C" void kernel_launch(void* const* d_in, const int* in_sizes, int n_in,
                              void* d_out, int out_size, void* d_ws, size_t ws_size,
                              hipStream_t stream) {
    const float* pred_p  = (const float*)d_in[0];
    const float* pred_f  = (const float*)d_in[1];
    const float* true_d  = (const float*)d_in[2];
    const float* p_mean  = (const float*)d_in[3];
    const float* p_scale = (const float*)d_in[4];
    const float* f_mean  = (const float*)d_in[5];
    const float* f_scale = (const float*)d_in[6];
    const float* d_mean  = (const float*)d_in[7];
    const float* d_scale = (const float*)d_in[8];
    const float* elev    = (const float*)d_in[9];
    const float* Rcoef   = (const float*)d_in[10];
    const int*   eidx    = (const int*)d_in[11];

    const int N = in_sizes[3];              // 50000
    const int E = in_sizes[10];             // 128000
    const int B = in_sizes[0] / N;          // 256

    const int* esrc = eidx;
    const int* edst = eidx + E;

    // workspace layout
    char* ws = (char*)d_ws;
    const size_t ht_bytes  = (size_t)N * B * sizeof(float);      // 51.2 MB
    const size_t acc_bytes = (size_t)N * B * sizeof(__half);     // 25.6 MB
    float*   HT    = (float*)ws;                                 // [N][B] f32
    __half2* acc2  = (__half2*)(ws + ht_bytes);                  // [N][B/2]
    double*  accum = (double*)(ws + ht_bytes + acc_bytes);       // [2]

    // zero acc2 + accumulators (HT is fully overwritten)
    hipMemsetAsync(acc2, 0, acc_bytes + 2 * sizeof(double), stream);

    const int gn = (N + TILE - 1) / TILE;   // 782
    const int gb = B / TILE;                // 4
    const int ge = E / TILE;                // 2000

    k_build_ht<<<dim3(gn, gb), 256, 0, stream>>>(pred_p, p_scale, p_mean, elev,
                                                 HT, B, N);
    k_edges<<<dim3(ge, gb), 256, 0, stream>>>(pred_f, f_scale, f_mean, Rcoef,
                                              esrc, edst, HT, acc2,
                                              accum + 1, B, E);
    k_mass<<<dim3(gn, gb), 256, 0, stream>>>(true_d, d_scale, d_mean, acc2,
                                             accum + 0, B, N);
    k_final<<<1, 1, 0, stream>>>(accum, (float*)d_out,
                                 1.0 / ((double)B * (double)N),
                                 1.0 / ((double)B * (double)E));
}

// Round 11
// 242.086 us; speedup vs baseline: 2.3658x; 1.0616x over previous
//
#include <hip/hip_runtime.h>
#include <hip/hip_fp16.h>

#define TILE 64

// packed fp16 atomic add (global_atomic_pk_add_f16)
typedef _Float16 f16x2 __attribute__((ext_vector_type(2)));
__device__ inline void pk_add(__half2* p, float a, float b) {
#if __has_builtin(__builtin_amdgcn_global_atomic_fadd_v2f16)
    f16x2 v; v[0] = (_Float16)a; v[1] = (_Float16)b;
    __builtin_amdgcn_global_atomic_fadd_v2f16(
        (__attribute__((address_space(1))) f16x2*)p, v);
#else
    __half2 v = __floats2half2_rn(a, b);
    unsafeAtomicAdd(p, v);
#endif
}

// ---------------------------------------------------------------------------
// Kernel 1: HTh[n*B + b] = fp16( pred_p[b*N+n]*p_scale[n] + p_mean[n] + elev[n] )
// 64x64 LDS transpose tile; coalesced f32 loads, half2 stores.
// ---------------------------------------------------------------------------
__global__ void k_build_ht(const float* __restrict__ pred_p,
                           const float* __restrict__ p_scale,
                           const float* __restrict__ p_mean,
                           const float* __restrict__ elev,
                           __half* __restrict__ HTh,
                           int B, int N) {
    __shared__ __align__(16) float tile[TILE][TILE + 2];
    const int n0 = blockIdx.x * TILE;
    const int b0 = blockIdx.y * TILE;
    const int tn = threadIdx.x % TILE;   // 0..63
    const int tw = threadIdx.x / TILE;   // 0..3

    const int n = n0 + tn;
    float sc = 0.f, mn = 0.f, el = 0.f;
    if (n < N) { sc = p_scale[n]; mn = p_mean[n]; el = elev[n]; }

    #pragma unroll
    for (int i = 0; i < TILE / 4; ++i) {
        const int bl = i * 4 + tw;
        float v = 0.f;
        if (n < N) v = pred_p[(size_t)(b0 + bl) * N + n] * sc + mn + el;
        tile[tn][bl] = v;
    }
    __syncthreads();

    // write 64 halves per node row as 32 half2 (128B per row-instr)
    const int c  = threadIdx.x & 31;     // batch pair
    const int rg = threadIdx.x >> 5;     // 0..7 row group
    #pragma unroll
    for (int i = 0; i < 8; ++i) {
        const int nl = i * 8 + rg;
        const int nn = n0 + nl;
        if (nn < N) {
            const float2 f = *reinterpret_cast<const float2*>(&tile[nl][2 * c]);
            __half2* dst = reinterpret_cast<__half2*>(HTh + (size_t)nn * B + b0);
            dst[c] = __floats2half2_rn(f.x, f.y);
        }
    }
}

// ---------------------------------------------------------------------------
// Kernel 2: per-edge fused work.
//   Phase A: hoist ALL 32 HT gathers (oldest in vmcnt queue -> never wait on
//            atomic completions; 32 loads in flight).
//   Phase B: head-loss VALU + pk-fp16 mass scatter.
// ---------------------------------------------------------------------------
__global__ void k_edges(const float* __restrict__ pred_f,
                        const float* __restrict__ f_scale,
                        const float* __restrict__ f_mean,
                        const float* __restrict__ Rcoef,
                        const int* __restrict__ esrc,
                        const int* __restrict__ edst,
                        const __half* __restrict__ HTh,   // [N][B] fp16
                        __half2* __restrict__ acc2,       // [N][B/2] fp16 pairs
                        double* __restrict__ head_accum,
                        int B, int E) {
    __shared__ __align__(16) float qt[TILE][TILE + 2];   // [e_local][b_local]
    __shared__ double wsum[4];
    const int e0 = blockIdx.x * TILE;
    const int b0 = blockIdx.y * TILE;
    const int te = threadIdx.x % TILE;
    const int tw = threadIdx.x / TILE;

    const int e = e0 + te;
    const float fs = f_scale[e];
    const float fm = f_mean[e];
    #pragma unroll
    for (int i = 0; i < TILE / 4; ++i) {
        const int bl = i * 4 + tw;
        qt[te][bl] = pred_f[(size_t)(b0 + bl) * E + e] * fs + fm;
    }
    __syncthreads();

    const int bl = te;                   // lane -> batch (coalesced HT/acc)
    const int halfB = B >> 1;
    const int pair0 = b0 >> 1;
    const __half* HTb = HTh + b0 + bl;

    // ---- Phase A: issue all 32 gathers (wave-uniform edge, lane=batch) ----
    int   sarr[16], darr[16];
    float hs[16], hd[16];
    #pragma unroll
    for (int j = 0; j < 16; ++j) {
        const int ee = e0 + tw * 16 + j;
        sarr[j] = esrc[ee];
        darr[j] = edst[ee];
        hs[j] = __half2float(HTb[(size_t)sarr[j] * B]);
        hd[j] = __half2float(HTb[(size_t)darr[j] * B]);
    }

    // ---- Phase B: VALU + atomics ----
    double head = 0.0;
    #pragma unroll
    for (int j = 0; j < 16; ++j) {
        const int el = tw * 16 + j;
        const int ee = e0 + el;
        const int s = sarr[j];
        const int d = darr[j];
        const float q = qt[el][bl];

        // |q|^0.852 = exp2(0.852*log2(|q|));  log2(0)=-inf -> exp2(-inf)=0
        const float aq = fabsf(q);
        const float pw = exp2f(0.852f * __log2f(aq));
        const float fr = Rcoef[ee] * q * pw;
        const float t = (hs[j] - hd[j]) - fr;
        head += (double)t * (double)t;

        // mass scatter: lanes 0..31 each cover a batch pair (2 fp16)
        if (bl < 32) {
            const float2 q01 = *reinterpret_cast<const float2*>(&qt[el][2 * bl]);
            pk_add(&acc2[(size_t)d * halfB + pair0 + bl],  q01.x,  q01.y);
            pk_add(&acc2[(size_t)s * halfB + pair0 + bl], -q01.x, -q01.y);
        }
    }

    #pragma unroll
    for (int off = 32; off >= 1; off >>= 1)
        head += __shfl_down(head, off, 64);
    if ((threadIdx.x & 63) == 0) wsum[threadIdx.x >> 6] = head;
    __syncthreads();
    if (threadIdx.x == 0)
        atomicAdd(head_accum, wsum[0] + wsum[1] + wsum[2] + wsum[3]);
}

// ---------------------------------------------------------------------------
// Kernel 3: loss_mass.  q_net read as half2 pairs from acc2; d from
// transposed true_d staged in LDS.
// ---------------------------------------------------------------------------
__global__ void k_mass(const float* __restrict__ true_d,
                       const float* __restrict__ d_scale,
                       const float* __restrict__ d_mean,
                       const __half2* __restrict__ acc2,  // [N][B/2]
                       double* __restrict__ mass_accum,
                       int B, int N) {
    __shared__ __align__(16) float dt[TILE][TILE + 2];  // [node][batch]
    __shared__ double wsum[4];
    const int n0 = blockIdx.x * TILE;
    const int b0 = blockIdx.y * TILE;
    const int tn = threadIdx.x % TILE;
    const int tw = threadIdx.x / TILE;
    const int halfB = B >> 1;

    const int n = n0 + tn;
    float sc = 0.f, mn = 0.f;
    if (n < N) { sc = d_scale[n]; mn = d_mean[n]; }
    #pragma unroll
    for (int i = 0; i < TILE / 4; ++i) {
        const int bl = i * 4 + tw;
        float v = 0.f;
        if (n < N) v = true_d[(size_t)(b0 + bl) * N + n] * sc + mn;
        dt[tn][bl] = v;
    }
    __syncthreads();

    double m = 0.0;
    const int tn2 = threadIdx.x & 31;      // pair column (2 batches)
    const int tg  = threadIdx.x >> 5;      // 0..7 row groups
    const int pair0 = b0 >> 1;
    #pragma unroll
    for (int j = 0; j < 8; ++j) {
        const int nl = j * 8 + tg;         // node row 0..63
        const int nn = n0 + nl;
        if (nn < N) {
            const __half2 h = acc2[(size_t)nn * halfB + pair0 + tn2];
            const float2 f = __half22float2(h);
            const float2 dv = *reinterpret_cast<const float2*>(&dt[nl][2 * tn2]);
            const float t0 = f.x - dv.x;
            const float t1 = f.y - dv.y;
            m += (double)t0 * (double)t0 + (double)t1 * (double)t1;
        }
    }
    #pragma unroll
    for (int off = 32; off >= 1; off >>= 1)
        m += __shfl_down(m, off, 64);
    if ((threadIdx.x & 63) == 0) wsum[threadIdx.x >> 6] = m;
    __syncthreads();
    if (threadIdx.x == 0)
        atomicAdd(mass_accum, wsum[0] + wsum[1] + wsum[2] + wsum[3]);
}

// ---------------------------------------------------------------------------
__global__ void k_final(const double* __restrict__ accum,
                        float* __restrict__ out,
                        double inv_mass_count, double inv_head_count) {
    out[0] = (float)(accum[0] * inv_mass_count);   // loss_mass
    out[1] = (float)(accum[1] * inv_head_count);   // loss_head
}

extern "C" void kernel_launch(void* const* d_in, const int* in_sizes, int n_in,
                              void* d_out, int out_size, void* d_ws, size_t ws_size,
                              hipStream_t stream) {
    const float* pred_p  = (const float*)d_in[0];
    const float* pred_f  = (const float*)d_in[1];
    const float* true_d  = (const float*)d_in[2];
    const float* p_mean  = (const float*)d_in[3];
    const float* p_scale = (const float*)d_in[4];
    const float* f_mean  = (const float*)d_in[5];
    const float* f_scale = (const float*)d_in[6];
    const float* d_mean  = (const float*)d_in[7];
    const float* d_scale = (const float*)d_in[8];
    const float* elev    = (const float*)d_in[9];
    const float* Rcoef   = (const float*)d_in[10];
    const int*   eidx    = (const int*)d_in[11];

    const int N = in_sizes[3];              // 50000
    const int E = in_sizes[10];             // 128000
    const int B = in_sizes[0] / N;          // 256

    const int* esrc = eidx;
    const int* edst = eidx + E;

    // workspace layout
    char* ws = (char*)d_ws;
    const size_t ht_bytes  = (size_t)N * B * sizeof(__half);     // 25.6 MB
    const size_t acc_bytes = (size_t)N * B * sizeof(__half);     // 25.6 MB
    __half*  HTh   = (__half*)ws;                                // [N][B] fp16
    __half2* acc2  = (__half2*)(ws + ht_bytes);                  // [N][B/2]
    double*  accum = (double*)(ws + ht_bytes + acc_bytes);       // [2]

    // zero acc2 + accumulators (HTh is fully overwritten)
    hipMemsetAsync(acc2, 0, acc_bytes + 2 * sizeof(double), stream);

    const int gn = (N + TILE - 1) / TILE;   // 782
    const int gb = B / TILE;                // 4
    const int ge = E / TILE;                // 2000

    k_build_ht<<<dim3(gn, gb), 256, 0, stream>>>(pred_p, p_scale, p_mean, elev,
                                                 HTh, B, N);
    k_edges<<<dim3(ge, gb), 256, 0, stream>>>(pred_f, f_scale, f_mean, Rcoef,
                                              esrc, edst, HTh, acc2,
                                              accum + 1, B, E);
    k_mass<<<dim3(gn, gb), 256, 0, stream>>>(true_d, d_scale, d_mean, acc2,
                                             accum + 0, B, N);
    k_final<<<1, 1, 0, stream>>>(accum, (float*)d_out,
                                 1.0 / ((double)B * (double)N),
                                 1.0 / ((double)B * (double)E));
}

// Round 12
// 238.117 us; speedup vs baseline: 2.4052x; 1.0167x over previous
//
#include <hip/hip_runtime.h>
#include <hip/hip_fp16.h>

#define TILE 64

// packed fp16 atomic add (global_atomic_pk_add_f16)
typedef _Float16 f16x2 __attribute__((ext_vector_type(2)));
__device__ inline void pk_add(__half2* p, float a, float b) {
#if __has_builtin(__builtin_amdgcn_global_atomic_fadd_v2f16)
    f16x2 v; v[0] = (_Float16)a; v[1] = (_Float16)b;
    __builtin_amdgcn_global_atomic_fadd_v2f16(
        (__attribute__((address_space(1))) f16x2*)p, v);
#else
    __half2 v = __floats2half2_rn(a, b);
    unsafeAtomicAdd(p, v);
#endif
}

// ---------------------------------------------------------------------------
// Kernel 1: HTh[n*B + b] = fp16( pred_p[b*N+n]*p_scale[n] + p_mean[n] + elev[n] )
// 64x64 LDS transpose tile; coalesced f32 loads, half2 stores.
// ---------------------------------------------------------------------------
__global__ void k_build_ht(const float* __restrict__ pred_p,
                           const float* __restrict__ p_scale,
                           const float* __restrict__ p_mean,
                           const float* __restrict__ elev,
                           __half* __restrict__ HTh,
                           int B, int N) {
    __shared__ __align__(16) float tile[TILE][TILE + 2];
    const int n0 = blockIdx.x * TILE;
    const int b0 = blockIdx.y * TILE;
    const int tn = threadIdx.x % TILE;   // 0..63
    const int tw = threadIdx.x / TILE;   // 0..3

    const int n = n0 + tn;
    float sc = 0.f, mn = 0.f, el = 0.f;
    if (n < N) { sc = p_scale[n]; mn = p_mean[n]; el = elev[n]; }

    #pragma unroll
    for (int i = 0; i < TILE / 4; ++i) {
        const int bl = i * 4 + tw;
        float v = 0.f;
        if (n < N) v = pred_p[(size_t)(b0 + bl) * N + n] * sc + mn + el;
        tile[tn][bl] = v;
    }
    __syncthreads();

    // write 64 halves per node row as 32 half2 (128B per row-instr)
    const int c  = threadIdx.x & 31;     // batch pair
    const int rg = threadIdx.x >> 5;     // 0..7 row group
    #pragma unroll
    for (int i = 0; i < 8; ++i) {
        const int nl = i * 8 + rg;
        const int nn = n0 + nl;
        if (nn < N) {
            const float2 f = *reinterpret_cast<const float2*>(&tile[nl][2 * c]);
            __half2* dst = reinterpret_cast<__half2*>(HTh + (size_t)nn * B + b0);
            dst[c] = __floats2half2_rn(f.x, f.y);
        }
    }
}

// ---------------------------------------------------------------------------
// Kernel 2: per-edge fused work.
//   Phase A : hoist ALL 32 HT gathers + edge indices.
//   Phase B1: head-loss VALU (lane = batch, 16 edges).
//   Phase B2: mass scatter, 2 edges per step, ALL 64 lanes active per
//             pk-atomic instruction (lanes 0-31 -> edge j, 32-63 -> edge j+1).
// ---------------------------------------------------------------------------
__global__ void k_edges(const float* __restrict__ pred_f,
                        const float* __restrict__ f_scale,
                        const float* __restrict__ f_mean,
                        const float* __restrict__ Rcoef,
                        const int* __restrict__ esrc,
                        const int* __restrict__ edst,
                        const __half* __restrict__ HTh,   // [N][B] fp16
                        __half2* __restrict__ acc2,       // [N][B/2] fp16 pairs
                        double* __restrict__ head_accum,
                        int B, int E) {
    __shared__ __align__(16) float qt[TILE][TILE + 2];   // [e_local][b_local]
    __shared__ double wsum[4];
    const int e0 = blockIdx.x * TILE;
    const int b0 = blockIdx.y * TILE;
    const int te = threadIdx.x % TILE;
    const int tw = threadIdx.x / TILE;

    const int e = e0 + te;
    const float fs = f_scale[e];
    const float fm = f_mean[e];
    #pragma unroll
    for (int i = 0; i < TILE / 4; ++i) {
        const int bl = i * 4 + tw;
        qt[te][bl] = pred_f[(size_t)(b0 + bl) * E + e] * fs + fm;
    }
    __syncthreads();

    const int bl = te;                   // lane -> batch (coalesced HT)
    const int halfB = B >> 1;
    const int pair0 = b0 >> 1;
    const __half* HTb = HTh + b0 + bl;

    // ---- Phase A: issue all 32 gathers (wave-uniform edge, lane=batch) ----
    int   sarr[16], darr[16];
    float hs[16], hd[16];
    #pragma unroll
    for (int j = 0; j < 16; ++j) {
        const int ee = e0 + tw * 16 + j;
        sarr[j] = esrc[ee];
        darr[j] = edst[ee];
        hs[j] = __half2float(HTb[(size_t)sarr[j] * B]);
        hd[j] = __half2float(HTb[(size_t)darr[j] * B]);
    }

    // ---- Phase B2 first: full-exec dual-edge scatter (no dependency on B1).
    // lanes 0-31 carry edge (2k), lanes 32-63 carry edge (2k+1).
    const int sel = bl >> 5;             // 0: low half, 1: high half
    const int pc  = bl & 31;             // pair column
    #pragma unroll
    for (int k = 0; k < 8; ++k) {
        const int el = tw * 16 + 2 * k + sel;          // this lane's edge
        const int d  = sel ? darr[2 * k + 1] : darr[2 * k];
        const int s  = sel ? sarr[2 * k + 1] : sarr[2 * k];
        const float2 q01 = *reinterpret_cast<const float2*>(&qt[el][2 * pc]);
        pk_add(&acc2[(size_t)d * halfB + pair0 + pc],  q01.x,  q01.y);
        pk_add(&acc2[(size_t)s * halfB + pair0 + pc], -q01.x, -q01.y);
    }

    // ---- Phase B1: head-loss VALU (lane = batch) ----
    double head = 0.0;
    #pragma unroll
    for (int j = 0; j < 16; ++j) {
        const int el = tw * 16 + j;
        const int ee = e0 + el;
        const float q = qt[el][bl];
        // |q|^0.852 = exp2(0.852*log2(|q|));  log2(0)=-inf -> exp2(-inf)=0
        const float aq = fabsf(q);
        const float pw = exp2f(0.852f * __log2f(aq));
        const float fr = Rcoef[ee] * q * pw;
        const float t = (hs[j] - hd[j]) - fr;
        head += (double)t * (double)t;
    }

    #pragma unroll
    for (int off = 32; off >= 1; off >>= 1)
        head += __shfl_down(head, off, 64);
    if ((threadIdx.x & 63) == 0) wsum[threadIdx.x >> 6] = head;
    __syncthreads();
    if (threadIdx.x == 0)
        atomicAdd(head_accum, wsum[0] + wsum[1] + wsum[2] + wsum[3]);
}

// ---------------------------------------------------------------------------
// Kernel 3: loss_mass.  q_net read as half2 pairs from acc2; d from
// transposed true_d staged in LDS.
// ---------------------------------------------------------------------------
__global__ void k_mass(const float* __restrict__ true_d,
                       const float* __restrict__ d_scale,
                       const float* __restrict__ d_mean,
                       const __half2* __restrict__ acc2,  // [N][B/2]
                       double* __restrict__ mass_accum,
                       int B, int N) {
    __shared__ __align__(16) float dt[TILE][TILE + 2];  // [node][batch]
    __shared__ double wsum[4];
    const int n0 = blockIdx.x * TILE;
    const int b0 = blockIdx.y * TILE;
    const int tn = threadIdx.x % TILE;
    const int tw = threadIdx.x / TILE;
    const int halfB = B >> 1;

    const int n = n0 + tn;
    float sc = 0.f, mn = 0.f;
    if (n < N) { sc = d_scale[n]; mn = d_mean[n]; }
    #pragma unroll
    for (int i = 0; i < TILE / 4; ++i) {
        const int bl = i * 4 + tw;
        float v = 0.f;
        if (n < N) v = true_d[(size_t)(b0 + bl) * N + n] * sc + mn;
        dt[tn][bl] = v;
    }
    __syncthreads();

    double m = 0.0;
    const int tn2 = threadIdx.x & 31;      // pair column (2 batches)
    const int tg  = threadIdx.x >> 5;      // 0..7 row groups
    const int pair0 = b0 >> 1;
    #pragma unroll
    for (int j = 0; j < 8; ++j) {
        const int nl = j * 8 + tg;         // node row 0..63
        const int nn = n0 + nl;
        if (nn < N) {
            const __half2 h = acc2[(size_t)nn * halfB + pair0 + tn2];
            const float2 f = __half22float2(h);
            const float2 dv = *reinterpret_cast<const float2*>(&dt[nl][2 * tn2]);
            const float t0 = f.x - dv.x;
            const float t1 = f.y - dv.y;
            m += (double)t0 * (double)t0 + (double)t1 * (double)t1;
        }
    }
    #pragma unroll
    for (int off = 32; off >= 1; off >>= 1)
        m += __shfl_down(m, off, 64);
    if ((threadIdx.x & 63) == 0) wsum[threadIdx.x >> 6] = m;
    __syncthreads();
    if (threadIdx.x == 0)
        atomicAdd(mass_accum, wsum[0] + wsum[1] + wsum[2] + wsum[3]);
}

// ---------------------------------------------------------------------------
__global__ void k_final(const double* __restrict__ accum,
                        float* __restrict__ out,
                        double inv_mass_count, double inv_head_count) {
    out[0] = (float)(accum[0] * inv_mass_count);   // loss_mass
    out[1] = (float)(accum[1] * inv_head_count);   // loss_head
}

extern "C" void kernel_launch(void* const* d_in, const int* in_sizes, int n_in,
                              void* d_out, int out_size, void* d_ws, size_t ws_size,
                              hipStream_t stream) {
    const float* pred_p  = (const float*)d_in[0];
    const float* pred_f  = (const float*)d_in[1];
    const float* true_d  = (const float*)d_in[2];
    const float* p_mean  = (const float*)d_in[3];
    const float* p_scale = (const float*)d_in[4];
    const float* f_mean  = (const float*)d_in[5];
    const float* f_scale = (const float*)d_in[6];
    const float* d_mean  = (const float*)d_in[7];
    const float* d_scale = (const float*)d_in[8];
    const float* elev    = (const float*)d_in[9];
    const float* Rcoef   = (const float*)d_in[10];
    const int*   eidx    = (const int*)d_in[11];

    const int N = in_sizes[3];              // 50000
    const int E = in_sizes[10];             // 128000
    const int B = in_sizes[0] / N;          // 256

    const int* esrc = eidx;
    const int* edst = eidx + E;

    // workspace layout
    char* ws = (char*)d_ws;
    const size_t ht_bytes  = (size_t)N * B * sizeof(__half);     // 25.6 MB
    const size_t acc_bytes = (size_t)N * B * sizeof(__half);     // 25.6 MB
    __half*  HTh   = (__half*)ws;                                // [N][B] fp16
    __half2* acc2  = (__half2*)(ws + ht_bytes);                  // [N][B/2]
    double*  accum = (double*)(ws + ht_bytes + acc_bytes);       // [2]

    // zero acc2 + accumulators (HTh is fully overwritten)
    hipMemsetAsync(acc2, 0, acc_bytes + 2 * sizeof(double), stream);

    const int gn = (N + TILE - 1) / TILE;   // 782
    const int gb = B / TILE;                // 4
    const int ge = E / TILE;                // 2000

    k_build_ht<<<dim3(gn, gb), 256, 0, stream>>>(pred_p, p_scale, p_mean, elev,
                                                 HTh, B, N);
    k_edges<<<dim3(ge, gb), 256, 0, stream>>>(pred_f, f_scale, f_mean, Rcoef,
                                              esrc, edst, HTh, acc2,
                                              accum + 1, B, E);
    k_mass<<<dim3(gn, gb), 256, 0, stream>>>(true_d, d_scale, d_mean, acc2,
                                             accum + 0, B, N);
    k_final<<<1, 1, 0, stream>>>(accum, (float*)d_out,
                                 1.0 / ((double)B * (double)N),
                                 1.0 / ((double)B * (double)E));
}